// Round 15
// baseline (278.486 us; speedup 1.0000x reference)
//
#include <hip/hip_runtime.h>
#include <hip/hip_fp16.h>

#define RN 4
#define XSTRIDE 132   // R + DIN

typedef float    frag_cd __attribute__((ext_vector_type(4)));
typedef _Float16 frag_h  __attribute__((ext_vector_type(8)));

#define CW_M  (6 * 128 * 128)
#define CW_A  (6 * 128 * 256)
#define CW_1  (128 * 128)
#define CW_2  (48 * 128)
#define CW_TOT (CW_M + CW_A + CW_1 + CW_2)

// ---------------- merged prep: weight converts + x convert + degree count ---
__global__ void prep_kernel(
    const float* __restrict__ Wm, const float* __restrict__ Wa,
    const float* __restrict__ W1, const float* __restrict__ W2,
    _Float16* __restrict__ WmT, _Float16* __restrict__ WaT,
    _Float16* __restrict__ W1T, _Float16* __restrict__ W2T,
    const float* __restrict__ x, _Float16* __restrict__ X,
    const int* __restrict__ ei, int* __restrict__ cnt, int N, int E)
{
    int id = blockIdx.x * 256 + threadIdx.x;
    if (id < CW_M) {
        const int K = 128;
        int per = K * 128;
        int lr = id / per;  int l = lr / 3, r = lr - l * 3;
        int rem = id - lr * per;
        int k = rem >> 7, col = rem & 127;
        WmT[((size_t)lr * 128 + col) * K + k] =
            (_Float16)Wm[(((size_t)l * 4 + r) * K + k) * 128 + col];
        return;
    }
    id -= CW_M;
    if (id < CW_A) {
        const int K = 256;
        int per = K * 128;
        int lr = id / per;  int l = lr / 3, r = lr - l * 3;
        int rem = id - lr * per;
        int k = rem >> 7, col = rem & 127;
        WaT[((size_t)lr * 128 + col) * K + k] =
            (_Float16)Wa[(((size_t)l * 4 + r) * K + k) * 128 + col];
        return;
    }
    id -= CW_A;
    if (id < CW_1) {
        int col = id >> 7, k = id & 127;
        W1T[id] = (_Float16)W1[k * 128 + col];
        return;
    }
    id -= CW_1;
    if (id < CW_2) {
        int col = id >> 7, k = id & 127;
        W2T[id] = (_Float16)((col < 40) ? W2[k * 40 + col] : 0.0f);
        return;
    }
    id -= CW_2;
    if (id < N * 16) {              // x convert: 8 floats -> 8 halves
        int n = id >> 4, g = id & 15;
        const float4* src = (const float4*)(x + (size_t)n * XSTRIDE + RN + g * 8);
        float4 f0 = src[0], f1 = src[1];
        __half2 h0 = __float22half2_rn(make_float2(f0.x, f0.y));
        __half2 h1 = __float22half2_rn(make_float2(f0.z, f0.w));
        __half2 h2 = __float22half2_rn(make_float2(f1.x, f1.y));
        __half2 h3 = __float22half2_rn(make_float2(f1.z, f1.w));
        uint4 st; st.x = *(uint*)&h0; st.y = *(uint*)&h1;
        st.z = *(uint*)&h2; st.w = *(uint*)&h3;
        ((uint4*)X)[(size_t)n * 16 + g] = st;
        return;
    }
    id -= N * 16;
    if (id < E) atomicAdd(&cnt[ei[E + id]], 1);
}

// ---------------- CSR scans ------------------------------------------------
__global__ void scanA(const int* __restrict__ cnt, int N, int* __restrict__ bsums) {
    __shared__ int s[256];
    int t = threadIdx.x, n = blockIdx.x * 256 + t;
    s[t] = (n < N) ? cnt[n] : 0;
    __syncthreads();
    for (int off = 128; off > 0; off >>= 1) {
        if (t < off) s[t] += s[t + off];
        __syncthreads();
    }
    if (t == 0) bsums[blockIdx.x] = s[0];
}

__global__ void scanC(const int* __restrict__ cnt, int N, int nb,
                      const int* __restrict__ bsums, int* __restrict__ offs) {
    __shared__ int s[256];
    __shared__ int basebuf[256];
    int t = threadIdx.x, n = blockIdx.x * 256 + t;
    int bid = blockIdx.x;
    basebuf[t] = (t < bid && t < nb) ? bsums[t] : 0;
    __syncthreads();
    for (int off = 128; off > 0; off >>= 1) {
        if (t < off) basebuf[t] += basebuf[t + off];
        __syncthreads();
    }
    int base = basebuf[0];
    int v = (n < N) ? cnt[n] : 0;
    s[t] = v; __syncthreads();
    for (int off = 1; off < 256; off <<= 1) {
        int add = (t >= off) ? s[t - off] : 0;
        __syncthreads();
        s[t] += add;
        __syncthreads();
    }
    if (n < N) {
        offs[n] = base + s[t] - v;
        if (n == N - 1) offs[N] = base + s[t];
    }
}

__global__ void fill_kernel(const int* __restrict__ ei, int E,
                            const int* __restrict__ offs, int* __restrict__ fc,
                            int* __restrict__ csr) {
    int e = blockIdx.x * 256 + threadIdx.x;
    if (e < E) {
        int dst = ei[E + e];
        int p = offs[dst] + atomicAdd(&fc[dst], 1);
        csr[p] = ei[e];
    }
}

// ---------------- aggregate: mean over in-edges of Mb (fp16) ---------------
__global__ __launch_bounds__(256) void agg_kernel(
    const int* __restrict__ csr, const int* __restrict__ offs,
    const _Float16* __restrict__ Mb, _Float16* __restrict__ S, int N)
{
    int node = blockIdx.x * 16 + (threadIdx.x >> 4);
    int lane = threadIdx.x & 15;
    if (node >= N) return;
    int lo = offs[node], hi = offs[node + 1];
    const uint4* M4 = (const uint4*)Mb;     // row = 16 x uint4
    float a[8];
    #pragma unroll
    for (int i = 0; i < 8; ++i) a[i] = 0.0f;
    int e = lo;
    for (; e + 3 < hi; e += 4) {
        #pragma unroll
        for (int j = 0; j < 4; ++j) {
            uint4 u = M4[(size_t)csr[e + j] * 16 + lane];
            float2 f0 = __half22float2(*(const __half2*)&u.x);
            float2 f1 = __half22float2(*(const __half2*)&u.y);
            float2 f2 = __half22float2(*(const __half2*)&u.z);
            float2 f3 = __half22float2(*(const __half2*)&u.w);
            a[0] += f0.x; a[1] += f0.y; a[2] += f1.x; a[3] += f1.y;
            a[4] += f2.x; a[5] += f2.y; a[6] += f3.x; a[7] += f3.y;
        }
    }
    for (; e < hi; ++e) {
        uint4 u = M4[(size_t)csr[e] * 16 + lane];
        float2 f0 = __half22float2(*(const __half2*)&u.x);
        float2 f1 = __half22float2(*(const __half2*)&u.y);
        float2 f2 = __half22float2(*(const __half2*)&u.z);
        float2 f3 = __half22float2(*(const __half2*)&u.w);
        a[0] += f0.x; a[1] += f0.y; a[2] += f1.x; a[3] += f1.y;
        a[4] += f2.x; a[5] += f2.y; a[6] += f3.x; a[7] += f3.y;
    }
    float inv = (hi > lo) ? 1.0f / (float)(hi - lo) : 0.0f;
    __half2 h0 = __float22half2_rn(make_float2(a[0] * inv, a[1] * inv));
    __half2 h1 = __float22half2_rn(make_float2(a[2] * inv, a[3] * inv));
    __half2 h2 = __float22half2_rn(make_float2(a[4] * inv, a[5] * inv));
    __half2 h3 = __float22half2_rn(make_float2(a[6] * inv, a[7] * inv));
    uint4 st; st.x = *(uint*)&h0; st.y = *(uint*)&h1;
    st.z = *(uint*)&h2; st.w = *(uint*)&h3;
    ((uint4*)S)[(size_t)node * 16 + lane] = st;
}

// ---- stage one [64][128] fp16 tile into padded LDS (512-thread blocks) ----
#define STAGE_TILE512(dst, src, n0, tid)                                      \
    _Pragma("unroll")                                                         \
    for (int i_ = 0; i_ < 2; ++i_) {                                          \
        int idx_ = i_ * 512 + (tid);                                          \
        int row_ = idx_ >> 4, g_ = idx_ & 15;                                 \
        *(uint4*)&(dst)[row_][g_ * 8] =                                       \
            ((const uint4*)(src))[((size_t)((n0) + row_)) * 16 + g_];         \
    }

// ---------------- layer-1 msg GEMM (512 thr, 8 waves x 16-col slices) ------
// 3 per-role accumulators: K-loop is pure MFMA (no VALU scaling);
// coefficients fold into the epilogue: out = relu(sum_r c_r (acc_r + b_r)).
__global__ __launch_bounds__(512, 4) void msg_kernel(
    const float* __restrict__ x,
    const _Float16* __restrict__ Fp,               // [N][128]
    const _Float16* __restrict__ W,                // [3][128][128]
    const float* __restrict__ bias,                // [4][128]
    _Float16* __restrict__ out)
{
    __shared__ _Float16 As[64][136];
    __shared__ float cc[64][3];

    const int tid = threadIdx.x;
    const int n0 = blockIdx.x * 64;
    const int lane = tid & 63;
    const int wv = tid >> 6;          // 0..7
    const int q = lane >> 4;
    const int lb = lane & 15;
    const int w16 = wv * 16;

    if (tid < 64) {
        const float* xr = x + (size_t)(n0 + tid) * XSTRIDE;
        cc[tid][0] = 2.0f * xr[0];
        cc[tid][1] = xr[1];
        cc[tid][2] = xr[2];
    }
    STAGE_TILE512(As, Fp, n0, tid)
    __syncthreads();

    frag_cd acc[3][4];
    #pragma unroll
    for (int r = 0; r < 3; ++r)
        #pragma unroll
        for (int nt = 0; nt < 4; ++nt) acc[r][nt] = (frag_cd){0.f, 0.f, 0.f, 0.f};

    // full B prefetch: 4 chunks x 3 roles (12 frags)
    frag_h bF[4][3];
    #pragma unroll
    for (int c = 0; c < 4; ++c)
        #pragma unroll
        for (int r = 0; r < 3; ++r)
            bF[c][r] = *(const frag_h*)(
                W + ((size_t)(r * 128 + w16 + lb)) * 128 + c * 32 + q * 8);

    #pragma unroll
    for (int c = 0; c < 4; ++c) {
        frag_h aL[4];
        #pragma unroll
        for (int nt = 0; nt < 4; ++nt)
            aL[nt] = *(const frag_h*)&As[nt * 16 + lb][c * 32 + q * 8];
        #pragma unroll
        for (int r = 0; r < 3; ++r)
            #pragma unroll
            for (int nt = 0; nt < 4; ++nt)
                acc[r][nt] = __builtin_amdgcn_mfma_f32_16x16x32_f16(
                    aL[nt], bF[c][r], acc[r][nt], 0, 0, 0);
    }

    {
        int col = w16 + lb;
        float b0 = bias[col], b1 = bias[128 + col], b2 = bias[256 + col];
        #pragma unroll
        for (int nt = 0; nt < 4; ++nt)
            #pragma unroll
            for (int rg = 0; rg < 4; ++rg) {
                int row = nt * 16 + q * 4 + rg;
                float v = cc[row][0] * (acc[0][nt][rg] + b0)
                        + cc[row][1] * (acc[1][nt][rg] + b1)
                        + cc[row][2] * (acc[2][nt][rg] + b2);
                out[(size_t)(n0 + row) * 128 + col] = (_Float16)fmaxf(v, 0.0f);
            }
    }
}

// ====== PHASE-A MACRO (512 thr): update GEMM KV=256, 3 role accumulators ====
// Pure-MFMA K-loop (A unscaled from LDS, B global depth-3); epilogue combines
// roles. Fs may alias As (As dead after chunk-3 reads; barrier before write).
#define UPDATE_PHASE_A_LDS(Wa_, ba_)                                          \
    frag_cd acc[3][4];                                                        \
    _Pragma("unroll")                                                         \
    for (int r = 0; r < 3; ++r)                                               \
        _Pragma("unroll")                                                     \
        for (int nt = 0; nt < 4; ++nt)                                        \
            acc[r][nt] = (frag_cd){0.f, 0.f, 0.f, 0.f};                       \
    size_t wrow[3];                                                           \
    _Pragma("unroll")                                                         \
    for (int r = 0; r < 3; ++r)                                               \
        wrow[r] = ((size_t)(r * 128 + w16 + lb)) * 256 + q * 8;               \
    {                                                                         \
        frag_h bF[3][3];                                                      \
        auto loadB = [&](int c, int buf) {                                    \
            _Pragma("unroll")                                                 \
            for (int r = 0; r < 3; ++r)                                       \
                bF[buf][r] = *(const frag_h*)((Wa_) + wrow[r] + c * 32);      \
        };                                                                    \
        loadB(0, 0);                                                          \
        loadB(1, 1);                                                          \
        _Pragma("unroll")                                                     \
        for (int ch = 0; ch < 8; ++ch) {                                      \
            if (ch + 2 < 8) loadB(ch + 2, (ch + 2) % 3);                      \
            frag_h aL[4];                                                     \
            _Pragma("unroll")                                                 \
            for (int nt = 0; nt < 4; ++nt)                                    \
                aL[nt] = (ch < 4)                                             \
                    ? *(const frag_h*)&As[nt * 16 + lb][ch * 32 + q * 8]      \
                    : *(const frag_h*)&Ss[nt * 16 + lb][(ch - 4) * 32 + q * 8]; \
            const int cur = ch % 3;                                           \
            _Pragma("unroll")                                                 \
            for (int r = 0; r < 3; ++r)                                       \
                _Pragma("unroll")                                             \
                for (int nt = 0; nt < 4; ++nt)                                \
                    acc[r][nt] = __builtin_amdgcn_mfma_f32_16x16x32_f16(      \
                        aL[nt], bF[cur][r], acc[r][nt], 0, 0, 0);             \
        }                                                                     \
    }                                                                         \
    float vv[4][4];                                                           \
    {                                                                         \
        int col = w16 + lb;                                                   \
        float b0 = (ba_)[col], b1 = (ba_)[128 + col], b2 = (ba_)[256 + col];  \
        _Pragma("unroll")                                                     \
        for (int nt = 0; nt < 4; ++nt)                                        \
            _Pragma("unroll")                                                 \
            for (int rg = 0; rg < 4; ++rg) {                                  \
                int row = nt * 16 + q * 4 + rg;                               \
                float v = cc[row][0] * (acc[0][nt][rg] + b0)                  \
                        + cc[row][1] * (acc[1][nt][rg] + b1)                  \
                        + cc[row][2] * (acc[2][nt][rg] + b2);                 \
                vv[nt][rg] = fmaxf(v, 0.0f);                                  \
            }                                                                 \
    }                                                                         \
    _Pragma("unroll")                                                         \
    for (int nt = 0; nt < 4; ++nt)                                            \
        _Pragma("unroll")                                                     \
        for (int rg = 0; rg < 4; ++rg) {                                      \
            float ss = vv[nt][rg] * vv[nt][rg];                               \
            _Pragma("unroll")                                                 \
            for (int m = 1; m < 16; m <<= 1) ss += __shfl_xor(ss, m, 64);     \
            if (lb == 0) red[nt * 16 + q * 4 + rg][wv] = ss;                  \
        }                                                                     \
    __syncthreads();  /* all K-loop LDS reads complete block-wide here */     \
    _Pragma("unroll")                                                         \
    for (int nt = 0; nt < 4; ++nt)                                            \
        _Pragma("unroll")                                                     \
        for (int rg = 0; rg < 4; ++rg) {                                      \
            int row = nt * 16 + q * 4 + rg;                                   \
            float t = (red[row][0] + red[row][1]) + (red[row][2] + red[row][3]) \
                    + (red[row][4] + red[row][5]) + (red[row][6] + red[row][7]); \
            float inv = 1.0f / fmaxf(sqrtf(t), 1e-12f);                       \
            Fs[row][w16 + lb] = (_Float16)(vv[nt][rg] * inv);                 \
        }                                                                     \
    __syncthreads();

// ---------------- fused: layer update (norm) + next-layer msg --------------
__global__ __launch_bounds__(512, 4) void fused_upd_msg(
    const float* __restrict__ x,
    const _Float16* __restrict__ Fp, const _Float16* __restrict__ Sp,
    const _Float16* __restrict__ Wa_, const float* __restrict__ ba_,
    const _Float16* __restrict__ Wm2, const float* __restrict__ bm2,
    _Float16* __restrict__ F1, _Float16* __restrict__ Mb)
{
    __shared__ _Float16 ldsbuf[2 * 64 * 136];
    __shared__ float cc[64][3];
    __shared__ float red[64][8];
    _Float16 (*As)[136] = (_Float16(*)[136])ldsbuf;
    _Float16 (*Ss)[136] = (_Float16(*)[136])(ldsbuf + 64 * 136);
    _Float16 (*Fs)[136] = As;   // alias: As dead after K-chunk 3

    const int tid = threadIdx.x;
    const int n0 = blockIdx.x * 64;
    const int lane = tid & 63;
    const int wv = tid >> 6;          // 0..7
    const int q = lane >> 4;
    const int lb = lane & 15;
    const int w16 = wv * 16;

    if (tid < 64) {
        const float* xr = x + (size_t)(n0 + tid) * XSTRIDE;
        cc[tid][0] = 2.0f * xr[0];
        cc[tid][1] = xr[1];
        cc[tid][2] = xr[2];
    }
    STAGE_TILE512(As, Fp, n0, tid)
    STAGE_TILE512(Ss, Sp, n0, tid)
    __syncthreads();

    UPDATE_PHASE_A_LDS(Wa_, ba_)

    // write F1 global, coalesced 16-B stores from LDS
    #pragma unroll
    for (int i = 0; i < 2; ++i) {
        int idx = i * 512 + tid;             // 0..1023
        int row = idx >> 4, g = idx & 15;
        ((uint4*)F1)[(size_t)(n0 + row) * 16 + g] = *(const uint4*)&Fs[row][g * 8];
    }

    // ---- Phase B: msg GEMM, A from LDS Fs, 3 role accumulators ----
    frag_cd a2[3][4];
    #pragma unroll
    for (int r = 0; r < 3; ++r)
        #pragma unroll
        for (int nt = 0; nt < 4; ++nt) a2[r][nt] = (frag_cd){0.f, 0.f, 0.f, 0.f};

    frag_h bB[4][3];
    #pragma unroll
    for (int c = 0; c < 4; ++c)
        #pragma unroll
        for (int r = 0; r < 3; ++r)
            bB[c][r] = *(const frag_h*)(
                Wm2 + ((size_t)(r * 128 + w16 + lb)) * 128 + c * 32 + q * 8);

    #pragma unroll
    for (int c = 0; c < 4; ++c) {
        frag_h aM[4];
        #pragma unroll
        for (int nt = 0; nt < 4; ++nt)
            aM[nt] = *(const frag_h*)&Fs[nt * 16 + lb][c * 32 + q * 8];
        #pragma unroll
        for (int r = 0; r < 3; ++r)
            #pragma unroll
            for (int nt = 0; nt < 4; ++nt)
                a2[r][nt] = __builtin_amdgcn_mfma_f32_16x16x32_f16(
                    aM[nt], bB[c][r], a2[r][nt], 0, 0, 0);
    }

    {
        int col = w16 + lb;
        float b0 = bm2[col], b1 = bm2[128 + col], b2 = bm2[256 + col];
        #pragma unroll
        for (int nt = 0; nt < 4; ++nt)
            #pragma unroll
            for (int rg = 0; rg < 4; ++rg) {
                int row = nt * 16 + q * 4 + rg;
                float v = cc[row][0] * (a2[0][nt][rg] + b0)
                        + cc[row][1] * (a2[1][nt][rg] + b1)
                        + cc[row][2] * (a2[2][nt][rg] + b2);
                Mb[(size_t)(n0 + row) * 128 + col] = (_Float16)fmaxf(v, 0.0f);
            }
    }
}

// ---------------- fused: layer-2 update + final MLP + log_softmax ----------
// Fs aliases As; Z aliases Ss. Phase C on waves 0-3 only.
__global__ __launch_bounds__(512, 4) void fused_upd_final(
    const float* __restrict__ x,
    const _Float16* __restrict__ Fp, const _Float16* __restrict__ Sp,
    const _Float16* __restrict__ Wa_, const float* __restrict__ ba_,
    const _Float16* __restrict__ W1T, const float* __restrict__ b1,
    const _Float16* __restrict__ W2T, const float* __restrict__ b2,
    float* __restrict__ out)
{
    __shared__ _Float16 ldsbuf[2 * 64 * 136];
    __shared__ float cc[64][3];
    __shared__ float red[64][8];
    _Float16 (*As)[136] = (_Float16(*)[136])ldsbuf;
    _Float16 (*Ss)[136] = (_Float16(*)[136])(ldsbuf + 64 * 136);
    _Float16 (*Fs)[136] = As;   // alias
    _Float16 (*Z)[136]  = Ss;   // alias

    const int tid = threadIdx.x;
    const int n0 = blockIdx.x * 64;
    const int lane = tid & 63;
    const int wv = tid >> 6;          // 0..7
    const int q = lane >> 4;
    const int lb = lane & 15;
    const int w16 = wv * 16;

    if (tid < 64) {
        const float* xr = x + (size_t)(n0 + tid) * XSTRIDE;
        cc[tid][0] = 2.0f * xr[0];
        cc[tid][1] = xr[1];
        cc[tid][2] = xr[2];
    }
    STAGE_TILE512(As, Fp, n0, tid)
    STAGE_TILE512(Ss, Sp, n0, tid)
    __syncthreads();

    UPDATE_PHASE_A_LDS(Wa_, ba_)

    // ---- Phase B: z = F2 @ W1 + b1 (A from LDS Fs, wave = 16-col slice) ----
    frag_cd az[4];
    #pragma unroll
    for (int nt = 0; nt < 4; ++nt) az[nt] = (frag_cd){0.f, 0.f, 0.f, 0.f};

    frag_h bZ[4];
    #pragma unroll
    for (int c = 0; c < 4; ++c)
        bZ[c] = *(const frag_h*)(W1T + (size_t)(w16 + lb) * 128 + c * 32 + q * 8);

    #pragma unroll
    for (int c = 0; c < 4; ++c) {
        frag_h aZ[4];
        #pragma unroll
        for (int nt = 0; nt < 4; ++nt)
            aZ[nt] = *(const frag_h*)&Fs[nt * 16 + lb][c * 32 + q * 8];
        #pragma unroll
        for (int nt = 0; nt < 4; ++nt)
            az[nt] = __builtin_amdgcn_mfma_f32_16x16x32_f16(aZ[nt], bZ[c], az[nt], 0, 0, 0);
    }
    __syncthreads();   // Ss K-loop reads done block-wide before Z overwrite
    {
        int col = w16 + lb;
        float bb = b1[col];
        #pragma unroll
        for (int nt = 0; nt < 4; ++nt)
            #pragma unroll
            for (int rg = 0; rg < 4; ++rg)
                Z[nt * 16 + q * 4 + rg][col] = (_Float16)(az[nt][rg] + bb);
    }
    __syncthreads();

    // ---- Phase C: logits = z@W2 + b2, waves 0-3 (wave = 16-row tile) ----
    if (wv < 4) {
        frag_cd a2[3];
        #pragma unroll
        for (int ct = 0; ct < 3; ++ct) a2[ct] = (frag_cd){0.f, 0.f, 0.f, 0.f};
        #pragma unroll
        for (int ch = 0; ch < 4; ++ch) {
            frag_h zF = *(const frag_h*)&Z[wv * 16 + lb][ch * 32 + q * 8];
            #pragma unroll
            for (int ct = 0; ct < 3; ++ct) {
                frag_h bF = *(const frag_h*)(W2T + (size_t)(ct * 16 + lb) * 128 + ch * 32 + q * 8);
                a2[ct] = __builtin_amdgcn_mfma_f32_16x16x32_f16(zF, bF, a2[ct], 0, 0, 0);
            }
        }

        float lg[3][4];
        #pragma unroll
        for (int ct = 0; ct < 3; ++ct) {
            int col = ct * 16 + lb;
            bool valid = col < 40;
            float bb = valid ? b2[col] : -1e30f;
            #pragma unroll
            for (int rg = 0; rg < 4; ++rg)
                lg[ct][rg] = valid ? (a2[ct][rg] + bb) : -1e30f;
        }
        #pragma unroll
        for (int rg = 0; rg < 4; ++rg) {
            float mx = fmaxf(fmaxf(lg[0][rg], lg[1][rg]), lg[2][rg]);
            #pragma unroll
            for (int m = 1; m < 16; m <<= 1) mx = fmaxf(mx, __shfl_xor(mx, m, 64));
            float sm = __expf(lg[0][rg] - mx) + __expf(lg[1][rg] - mx) + __expf(lg[2][rg] - mx);
            #pragma unroll
            for (int m = 1; m < 16; m <<= 1) sm += __shfl_xor(sm, m, 64);
            float ls = mx + __logf(sm);
            int row = n0 + wv * 16 + q * 4 + rg;
            #pragma unroll
            for (int ct = 0; ct < 3; ++ct) {
                int col = ct * 16 + lb;
                if (col < 40) out[(size_t)row * 40 + col] = lg[ct][rg] - ls;
            }
        }
    }
}

extern "C" void kernel_launch(void* const* d_in, const int* in_sizes, int n_in,
                              void* d_out, int out_size, void* d_ws, size_t ws_size,
                              hipStream_t stream) {
    const float* x  = (const float*)d_in[0];
    const int*   ei = (const int*)d_in[1];
    const float* Wm = (const float*)d_in[2];
    const float* bm = (const float*)d_in[3];
    const float* Wa = (const float*)d_in[4];
    const float* ba = (const float*)d_in[5];
    const float* W1 = (const float*)d_in[6];
    const float* b1 = (const float*)d_in[7];
    const float* W2 = (const float*)d_in[8];
    const float* b2 = (const float*)d_in[9];
    float* out = (float*)d_out;

    const int N = in_sizes[0] / XSTRIDE;   // 40000
    const int E = in_sizes[1] / 2;         // 480000
    const int NB = (N + 255) / 256;        // 157
    const size_t P = (size_t)N * 128;      // plane elements

    // workspace carve (16B-aligned)
    _Float16* Mb  = (_Float16*)d_ws;       // msg fp16
    _Float16* X   = Mb + P;                // x feats fp16
    _Float16* S   = X + P;                 // aggr fp16
    _Float16* F1  = S + P;                 // layer-1 out fp16
    _Float16* WmT = F1 + P;
    _Float16* WaT = WmT + CW_M;
    _Float16* W1T = WaT + CW_A;
    _Float16* W2T = W1T + CW_1;
    int* cnt   = (int*)(W2T + CW_2);       // N (memset together with fc)
    int* fc    = cnt + N;                  // N
    int* offs  = fc + N;                   // N+1
    int* csr   = offs + N + 1;             // E
    int* bsums = csr + E;                  // NB

    // ---- prep: zero counters, then merged convert+count ----
    hipMemsetAsync(cnt, 0, (size_t)2 * N * sizeof(int), stream);
    const int prep_total = CW_TOT + N * 16 + E;
    prep_kernel<<<(prep_total + 255) / 256, 256, 0, stream>>>(
        Wm, Wa, W1, W2, WmT, WaT, W1T, W2T, x, X, ei, cnt, N, E);

    // ---- CSR: scanA -> scanC(inline scanB) -> fill ----
    scanA<<<NB, 256, 0, stream>>>(cnt, N, bsums);
    scanC<<<NB, 256, 0, stream>>>(cnt, N, NB, bsums, offs);
    fill_kernel<<<(E + 255) / 256, 256, 0, stream>>>(ei, E, offs, fc, csr);

    const int gblk = N / 64;               // 625
    const int ablk = (N + 15) / 16;        // 2500

    // layer 1 msg
    msg_kernel<<<gblk, 512, 0, stream>>>(x, X, WmT, bm, Mb);
    agg_kernel<<<ablk, 256, 0, stream>>>(csr, offs, Mb, S, N);
    // layer-1 update + layer-2 msg (fused)
    fused_upd_msg<<<gblk, 512, 0, stream>>>(
        x, X, S, WaT, ba,
        WmT + (size_t)3 * 128 * 128, bm + (size_t)4 * 128, F1, Mb);
    agg_kernel<<<ablk, 256, 0, stream>>>(csr, offs, Mb, S, N);
    // layer-2 update + final MLP + log_softmax (fused)
    fused_upd_final<<<gblk, 512, 0, stream>>>(
        x, F1, S, WaT + (size_t)3 * 128 * 256, ba + (size_t)4 * 128,
        W1T, b1, W2T, b2, out);
}

// Round 16
// 254.250 us; speedup vs baseline: 1.0953x; 1.0953x over previous
//
#include <hip/hip_runtime.h>
#include <hip/hip_fp16.h>

#define RN 4
#define XSTRIDE 132   // R + DIN

typedef float    frag_cd __attribute__((ext_vector_type(4)));
typedef _Float16 frag_h  __attribute__((ext_vector_type(8)));

#define CW_M  (6 * 128 * 128)
#define CW_A  (6 * 128 * 256)
#define CW_1  (128 * 128)
#define CW_2  (48 * 128)
#define CW_TOT (CW_M + CW_A + CW_1 + CW_2)

// ---------------- merged prep: weight converts + x convert + degree count ---
__global__ void prep_kernel(
    const float* __restrict__ Wm, const float* __restrict__ Wa,
    const float* __restrict__ W1, const float* __restrict__ W2,
    _Float16* __restrict__ WmT, _Float16* __restrict__ WaT,
    _Float16* __restrict__ W1T, _Float16* __restrict__ W2T,
    const float* __restrict__ x, _Float16* __restrict__ X,
    const int* __restrict__ ei, int* __restrict__ cnt, int N, int E)
{
    int id = blockIdx.x * 256 + threadIdx.x;
    if (id < CW_M) {
        const int K = 128;
        int per = K * 128;
        int lr = id / per;  int l = lr / 3, r = lr - l * 3;
        int rem = id - lr * per;
        int k = rem >> 7, col = rem & 127;
        WmT[((size_t)lr * 128 + col) * K + k] =
            (_Float16)Wm[(((size_t)l * 4 + r) * K + k) * 128 + col];
        return;
    }
    id -= CW_M;
    if (id < CW_A) {
        const int K = 256;
        int per = K * 128;
        int lr = id / per;  int l = lr / 3, r = lr - l * 3;
        int rem = id - lr * per;
        int k = rem >> 7, col = rem & 127;
        WaT[((size_t)lr * 128 + col) * K + k] =
            (_Float16)Wa[(((size_t)l * 4 + r) * K + k) * 128 + col];
        return;
    }
    id -= CW_A;
    if (id < CW_1) {
        int col = id >> 7, k = id & 127;
        W1T[id] = (_Float16)W1[k * 128 + col];
        return;
    }
    id -= CW_1;
    if (id < CW_2) {
        int col = id >> 7, k = id & 127;
        W2T[id] = (_Float16)((col < 40) ? W2[k * 40 + col] : 0.0f);
        return;
    }
    id -= CW_2;
    if (id < N * 16) {              // x convert: 8 floats -> 8 halves
        int n = id >> 4, g = id & 15;
        const float4* src = (const float4*)(x + (size_t)n * XSTRIDE + RN + g * 8);
        float4 f0 = src[0], f1 = src[1];
        __half2 h0 = __float22half2_rn(make_float2(f0.x, f0.y));
        __half2 h1 = __float22half2_rn(make_float2(f0.z, f0.w));
        __half2 h2 = __float22half2_rn(make_float2(f1.x, f1.y));
        __half2 h3 = __float22half2_rn(make_float2(f1.z, f1.w));
        uint4 st; st.x = *(uint*)&h0; st.y = *(uint*)&h1;
        st.z = *(uint*)&h2; st.w = *(uint*)&h3;
        ((uint4*)X)[(size_t)n * 16 + g] = st;
        return;
    }
    id -= N * 16;
    if (id < E) atomicAdd(&cnt[ei[E + id]], 1);
}

// ---------------- CSR scans ------------------------------------------------
__global__ void scanA(const int* __restrict__ cnt, int N, int* __restrict__ bsums) {
    __shared__ int s[256];
    int t = threadIdx.x, n = blockIdx.x * 256 + t;
    s[t] = (n < N) ? cnt[n] : 0;
    __syncthreads();
    for (int off = 128; off > 0; off >>= 1) {
        if (t < off) s[t] += s[t + off];
        __syncthreads();
    }
    if (t == 0) bsums[blockIdx.x] = s[0];
}

__global__ void scanC(const int* __restrict__ cnt, int N, int nb,
                      const int* __restrict__ bsums, int* __restrict__ offs) {
    __shared__ int s[256];
    __shared__ int basebuf[256];
    int t = threadIdx.x, n = blockIdx.x * 256 + t;
    int bid = blockIdx.x;
    basebuf[t] = (t < bid && t < nb) ? bsums[t] : 0;
    __syncthreads();
    for (int off = 128; off > 0; off >>= 1) {
        if (t < off) basebuf[t] += basebuf[t + off];
        __syncthreads();
    }
    int base = basebuf[0];
    int v = (n < N) ? cnt[n] : 0;
    s[t] = v; __syncthreads();
    for (int off = 1; off < 256; off <<= 1) {
        int add = (t >= off) ? s[t - off] : 0;
        __syncthreads();
        s[t] += add;
        __syncthreads();
    }
    if (n < N) {
        offs[n] = base + s[t] - v;
        if (n == N - 1) offs[N] = base + s[t];
    }
}

// ---------------- aggregate: mean over in-edges of Mb (fp16) ---------------
__global__ __launch_bounds__(256) void agg_kernel(
    const int* __restrict__ csr, const int* __restrict__ offs,
    const _Float16* __restrict__ Mb, _Float16* __restrict__ S, int N)
{
    int node = blockIdx.x * 16 + (threadIdx.x >> 4);
    int lane = threadIdx.x & 15;
    if (node >= N) return;
    int lo = offs[node], hi = offs[node + 1];
    const uint4* M4 = (const uint4*)Mb;     // row = 16 x uint4
    float a[8];
    #pragma unroll
    for (int i = 0; i < 8; ++i) a[i] = 0.0f;
    int e = lo;
    for (; e + 3 < hi; e += 4) {
        #pragma unroll
        for (int j = 0; j < 4; ++j) {
            uint4 u = M4[(size_t)csr[e + j] * 16 + lane];
            float2 f0 = __half22float2(*(const __half2*)&u.x);
            float2 f1 = __half22float2(*(const __half2*)&u.y);
            float2 f2 = __half22float2(*(const __half2*)&u.z);
            float2 f3 = __half22float2(*(const __half2*)&u.w);
            a[0] += f0.x; a[1] += f0.y; a[2] += f1.x; a[3] += f1.y;
            a[4] += f2.x; a[5] += f2.y; a[6] += f3.x; a[7] += f3.y;
        }
    }
    for (; e < hi; ++e) {
        uint4 u = M4[(size_t)csr[e] * 16 + lane];
        float2 f0 = __half22float2(*(const __half2*)&u.x);
        float2 f1 = __half22float2(*(const __half2*)&u.y);
        float2 f2 = __half22float2(*(const __half2*)&u.z);
        float2 f3 = __half22float2(*(const __half2*)&u.w);
        a[0] += f0.x; a[1] += f0.y; a[2] += f1.x; a[3] += f1.y;
        a[4] += f2.x; a[5] += f2.y; a[6] += f3.x; a[7] += f3.y;
    }
    float inv = (hi > lo) ? 1.0f / (float)(hi - lo) : 0.0f;
    __half2 h0 = __float22half2_rn(make_float2(a[0] * inv, a[1] * inv));
    __half2 h1 = __float22half2_rn(make_float2(a[2] * inv, a[3] * inv));
    __half2 h2 = __float22half2_rn(make_float2(a[4] * inv, a[5] * inv));
    __half2 h3 = __float22half2_rn(make_float2(a[6] * inv, a[7] * inv));
    uint4 st; st.x = *(uint*)&h0; st.y = *(uint*)&h1;
    st.z = *(uint*)&h2; st.w = *(uint*)&h3;
    ((uint4*)S)[(size_t)node * 16 + lane] = st;
}

// ---- helper: stage one [64][128] fp16 global plane tile into padded LDS ----
#define STAGE_TILE(dst, src, n0, tid)                                         \
    _Pragma("unroll")                                                         \
    for (int i_ = 0; i_ < 4; ++i_) {                                          \
        int idx_ = i_ * 256 + (tid);                                          \
        int row_ = idx_ >> 4, g_ = idx_ & 15;                                 \
        *(uint4*)&(dst)[row_][g_ * 8] =                                       \
            ((const uint4*)(src))[((size_t)((n0) + row_)) * 16 + g_];         \
    }

// ---------------- merged: layer-1 msg GEMM + CSR fill ----------------------
// Blocks [0,msgB): msg GEMM (A from LDS, full B prefetch, role-scaled A).
// Blocks [msgB,..): CSR fill scatter. Both depend only on prep/scanC ->
// independent, co-resident; disjoint bottlenecks overlap.
__global__ __launch_bounds__(256) void msg_fill_kernel(
    const float* __restrict__ x,
    const _Float16* __restrict__ Fp,               // [N][128]
    const _Float16* __restrict__ W,                // [3][128][128]
    const float* __restrict__ bias,                // [4][128]
    _Float16* __restrict__ out,
    const int* __restrict__ ei, int E,
    const int* __restrict__ offs, int* __restrict__ fc,
    int* __restrict__ csr, int msgB)
{
    __shared__ _Float16 As[64][136];
    __shared__ float cc[64][3];

    const int tid = threadIdx.x;
    if (blockIdx.x >= msgB) {   // ---- fill path ----
        int e = (blockIdx.x - msgB) * 256 + tid;
        if (e < E) {
            int dst = ei[E + e];
            int p = offs[dst] + atomicAdd(&fc[dst], 1);
            csr[p] = ei[e];
        }
        return;
    }

    // ---- msg path ----
    const int n0 = blockIdx.x * 64;
    const int lane = tid & 63;
    const int wv = tid >> 6;
    const int q = lane >> 4;
    const int lb = lane & 15;
    const int w32 = wv * 32;

    if (tid < 64) {
        const float* xr = x + (size_t)(n0 + tid) * XSTRIDE;
        cc[tid][0] = 2.0f * xr[0];
        cc[tid][1] = xr[1];
        cc[tid][2] = xr[2];
    }
    STAGE_TILE(As, Fp, n0, tid)
    __syncthreads();

    _Float16 ch16[4][3];
    #pragma unroll
    for (int nt = 0; nt < 4; ++nt)
        #pragma unroll
        for (int r = 0; r < 3; ++r)
            ch16[nt][r] = (_Float16)cc[nt * 16 + lb][r];

    frag_cd acc[4][2];
    #pragma unroll
    for (int nt = 0; nt < 4; ++nt)
        #pragma unroll
        for (int ct = 0; ct < 2; ++ct)
            acc[nt][ct] = (frag_cd){0.f, 0.f, 0.f, 0.f};

    frag_h bF[4][6];
    #pragma unroll
    for (int c = 0; c < 4; ++c)
        #pragma unroll
        for (int r = 0; r < 3; ++r)
            #pragma unroll
            for (int ct = 0; ct < 2; ++ct)
                bF[c][r * 2 + ct] = *(const frag_h*)(
                    W + ((size_t)(r * 128 + w32 + ct * 16 + lb)) * 128 + c * 32 + q * 8);

    frag_h aL[2][4];
    #pragma unroll
    for (int nt = 0; nt < 4; ++nt)
        aL[0][nt] = *(const frag_h*)&As[nt * 16 + lb][q * 8];

    #pragma unroll
    for (int c = 0; c < 4; ++c) {
        if (c + 1 < 4) {
            #pragma unroll
            for (int nt = 0; nt < 4; ++nt)
                aL[(c + 1) & 1][nt] = *(const frag_h*)&As[nt * 16 + lb][(c + 1) * 32 + q * 8];
        }
        #pragma unroll
        for (int r = 0; r < 3; ++r)
            #pragma unroll
            for (int nt = 0; nt < 4; ++nt) {
                frag_h sa = aL[c & 1][nt] * ch16[nt][r];
                #pragma unroll
                for (int ct = 0; ct < 2; ++ct)
                    acc[nt][ct] = __builtin_amdgcn_mfma_f32_16x16x32_f16(
                        sa, bF[c][r * 2 + ct], acc[nt][ct], 0, 0, 0);
            }
    }

    #pragma unroll
    for (int ct = 0; ct < 2; ++ct) {
        int col = w32 + ct * 16 + lb;
        float b0 = bias[col], b1 = bias[128 + col], b2 = bias[256 + col];
        #pragma unroll
        for (int nt = 0; nt < 4; ++nt)
            #pragma unroll
            for (int rg = 0; rg < 4; ++rg) {
                int row = nt * 16 + q * 4 + rg;
                float v = acc[nt][ct][rg]
                        + cc[row][0] * b0 + cc[row][1] * b1 + cc[row][2] * b2;
                out[(size_t)(n0 + row) * 128 + col] = (_Float16)fmaxf(v, 0.0f);
            }
    }
}

// ====== PHASE-A MACRO: update GEMM (KV=256), A from LDS, FULL B prefetch ====
// All 48 B-frags (192 VGPR) loaded up front -> zero vmcnt stalls in K-loop;
// A ping-pong from LDS hides ds_read latency. Fs may alias As (As dead after
// chunk-3 reads; barrier before write).
#define UPDATE_PHASE_A_LDS(Wa_, ba_)                                          \
    _Float16 ch16[4][3];                                                      \
    _Pragma("unroll")                                                         \
    for (int nt = 0; nt < 4; ++nt)                                            \
        _Pragma("unroll")                                                     \
        for (int r = 0; r < 3; ++r)                                           \
            ch16[nt][r] = (_Float16)cc[nt * 16 + lb][r];                      \
    frag_cd acc[4][2];                                                        \
    _Pragma("unroll")                                                         \
    for (int nt = 0; nt < 4; ++nt)                                            \
        _Pragma("unroll")                                                     \
        for (int ct = 0; ct < 2; ++ct)                                        \
            acc[nt][ct] = (frag_cd){0.f, 0.f, 0.f, 0.f};                      \
    size_t wrow[3][2];                                                        \
    _Pragma("unroll")                                                         \
    for (int r = 0; r < 3; ++r)                                               \
        _Pragma("unroll")                                                     \
        for (int ct = 0; ct < 2; ++ct)                                        \
            wrow[r][ct] = ((size_t)(r * 128 + w32 + ct * 16 + lb)) * 256 + q * 8; \
    {                                                                         \
        frag_h bF[8][6];                                                      \
        _Pragma("unroll")                                                     \
        for (int c = 0; c < 8; ++c)                                           \
            _Pragma("unroll")                                                 \
            for (int r = 0; r < 3; ++r)                                       \
                _Pragma("unroll")                                             \
                for (int ct = 0; ct < 2; ++ct)                                \
                    bF[c][r * 2 + ct] = *(const frag_h*)((Wa_) + wrow[r][ct] + c * 32); \
        frag_h aL[2][4];                                                      \
        _Pragma("unroll")                                                     \
        for (int nt = 0; nt < 4; ++nt)                                        \
            aL[0][nt] = *(const frag_h*)&As[nt * 16 + lb][q * 8];             \
        _Pragma("unroll")                                                     \
        for (int ch = 0; ch < 8; ++ch) {                                      \
            if (ch + 1 < 8) {                                                 \
                const int c1 = ch + 1;                                        \
                _Pragma("unroll")                                             \
                for (int nt = 0; nt < 4; ++nt)                                \
                    aL[c1 & 1][nt] = (c1 < 4)                                 \
                        ? *(const frag_h*)&As[nt * 16 + lb][c1 * 32 + q * 8]  \
                        : *(const frag_h*)&Ss[nt * 16 + lb][(c1 - 4) * 32 + q * 8]; \
            }                                                                 \
            _Pragma("unroll")                                                 \
            for (int r = 0; r < 3; ++r)                                       \
                _Pragma("unroll")                                             \
                for (int nt = 0; nt < 4; ++nt) {                              \
                    frag_h sa = aL[ch & 1][nt] * ch16[nt][r];                 \
                    _Pragma("unroll")                                         \
                    for (int ct = 0; ct < 2; ++ct)                            \
                        acc[nt][ct] = __builtin_amdgcn_mfma_f32_16x16x32_f16( \
                            sa, bF[ch][r * 2 + ct], acc[nt][ct], 0, 0, 0);    \
                }                                                             \
        }                                                                     \
    }                                                                         \
    float vv[4][2][4];                                                        \
    _Pragma("unroll")                                                         \
    for (int ct = 0; ct < 2; ++ct) {                                          \
        int col = w32 + ct * 16 + lb;                                         \
        float b0 = (ba_)[col], b1 = (ba_)[128 + col], b2 = (ba_)[256 + col];  \
        _Pragma("unroll")                                                     \
        for (int nt = 0; nt < 4; ++nt)                                        \
            _Pragma("unroll")                                                 \
            for (int rg = 0; rg < 4; ++rg) {                                  \
                int row = nt * 16 + q * 4 + rg;                               \
                float v = acc[nt][ct][rg]                                     \
                        + cc[row][0] * b0 + cc[row][1] * b1 + cc[row][2] * b2;\
                vv[nt][ct][rg] = fmaxf(v, 0.0f);                              \
            }                                                                 \
    }                                                                         \
    _Pragma("unroll")                                                         \
    for (int nt = 0; nt < 4; ++nt)                                            \
        _Pragma("unroll")                                                     \
        for (int rg = 0; rg < 4; ++rg) {                                      \
            float ss = vv[nt][0][rg] * vv[nt][0][rg] + vv[nt][1][rg] * vv[nt][1][rg]; \
            _Pragma("unroll")                                                 \
            for (int m = 1; m < 16; m <<= 1) ss += __shfl_xor(ss, m, 64);     \
            if (lb == 0) red[nt * 16 + q * 4 + rg][wv] = ss;                  \
        }                                                                     \
    __syncthreads();  /* all K-loop LDS reads complete block-wide here */     \
    _Pragma("unroll")                                                         \
    for (int nt = 0; nt < 4; ++nt)                                            \
        _Pragma("unroll")                                                     \
        for (int rg = 0; rg < 4; ++rg) {                                      \
            int row = nt * 16 + q * 4 + rg;                                   \
            float t = red[row][0] + red[row][1] + red[row][2] + red[row][3];  \
            float inv = 1.0f / fmaxf(sqrtf(t), 1e-12f);                       \
            _Pragma("unroll")                                                 \
            for (int ct = 0; ct < 2; ++ct)                                    \
                Fs[row][w32 + ct * 16 + lb] = (_Float16)(vv[nt][ct][rg] * inv); \
        }                                                                     \
    __syncthreads();

// ---------------- fused: layer update (norm) + next-layer msg --------------
// Fs ALIASES As. 36.6 KB LDS. 2 waves/SIMD -> 256 VGPR budget for full-B.
__global__ __launch_bounds__(256, 2) void fused_upd_msg(
    const float* __restrict__ x,
    const _Float16* __restrict__ Fp, const _Float16* __restrict__ Sp,
    const _Float16* __restrict__ Wa_, const float* __restrict__ ba_,
    const _Float16* __restrict__ Wm2, const float* __restrict__ bm2,
    _Float16* __restrict__ F1, _Float16* __restrict__ Mb)
{
    __shared__ _Float16 ldsbuf[2 * 64 * 136];
    __shared__ float cc[64][3];
    __shared__ float red[64][4];
    _Float16 (*As)[136] = (_Float16(*)[136])ldsbuf;
    _Float16 (*Ss)[136] = (_Float16(*)[136])(ldsbuf + 64 * 136);
    _Float16 (*Fs)[136] = As;   // alias: As dead after K-chunk 3

    const int tid = threadIdx.x;
    const int n0 = blockIdx.x * 64;
    const int lane = tid & 63;
    const int wv = tid >> 6;
    const int q = lane >> 4;
    const int lb = lane & 15;
    const int w32 = wv * 32;

    if (tid < 64) {
        const float* xr = x + (size_t)(n0 + tid) * XSTRIDE;
        cc[tid][0] = 2.0f * xr[0];
        cc[tid][1] = xr[1];
        cc[tid][2] = xr[2];
    }
    STAGE_TILE(As, Fp, n0, tid)
    STAGE_TILE(Ss, Sp, n0, tid)
    __syncthreads();

    UPDATE_PHASE_A_LDS(Wa_, ba_)

    // write F1 global, coalesced 16-B stores from LDS
    #pragma unroll
    for (int i = 0; i < 4; ++i) {
        int idx = i * 256 + tid;             // 0..1023
        int row = idx >> 4, g = idx & 15;
        ((uint4*)F1)[(size_t)(n0 + row) * 16 + g] = *(const uint4*)&Fs[row][g * 8];
    }

    // ---- Phase B: msg GEMM, A from LDS Fs, full B prefetch ----
    frag_cd a2[4][2];
    #pragma unroll
    for (int nt = 0; nt < 4; ++nt)
        #pragma unroll
        for (int ct = 0; ct < 2; ++ct)
            a2[nt][ct] = (frag_cd){0.f, 0.f, 0.f, 0.f};

    frag_h bB[4][6];
    #pragma unroll
    for (int c = 0; c < 4; ++c)
        #pragma unroll
        for (int r = 0; r < 3; ++r)
            #pragma unroll
            for (int ct = 0; ct < 2; ++ct)
                bB[c][r * 2 + ct] = *(const frag_h*)(
                    Wm2 + ((size_t)(r * 128 + w32 + ct * 16 + lb)) * 128 + c * 32 + q * 8);

    #pragma unroll
    for (int c = 0; c < 4; ++c) {
        frag_h aM[4];
        #pragma unroll
        for (int nt = 0; nt < 4; ++nt)
            aM[nt] = *(const frag_h*)&Fs[nt * 16 + lb][c * 32 + q * 8];
        #pragma unroll
        for (int r = 0; r < 3; ++r)
            #pragma unroll
            for (int nt = 0; nt < 4; ++nt) {
                frag_h sa = aM[nt] * ch16[nt][r];
                #pragma unroll
                for (int ct = 0; ct < 2; ++ct)
                    a2[nt][ct] = __builtin_amdgcn_mfma_f32_16x16x32_f16(
                        sa, bB[c][r * 2 + ct], a2[nt][ct], 0, 0, 0);
            }
    }

    #pragma unroll
    for (int ct = 0; ct < 2; ++ct) {
        int col = w32 + ct * 16 + lb;
        float b0 = bm2[col], b1 = bm2[128 + col], b2 = bm2[256 + col];
        #pragma unroll
        for (int nt = 0; nt < 4; ++nt)
            #pragma unroll
            for (int rg = 0; rg < 4; ++rg) {
                int row = nt * 16 + q * 4 + rg;
                float v = a2[nt][ct][rg]
                        + cc[row][0] * b0 + cc[row][1] * b1 + cc[row][2] * b2;
                Mb[(size_t)(n0 + row) * 128 + col] = (_Float16)fmaxf(v, 0.0f);
            }
    }
}

// ---------------- fused: layer-2 update + final MLP + log_softmax ----------
// Fs aliases As; Z aliases Ss. 36.6 KB LDS.
__global__ __launch_bounds__(256, 2) void fused_upd_final(
    const float* __restrict__ x,
    const _Float16* __restrict__ Fp, const _Float16* __restrict__ Sp,
    const _Float16* __restrict__ Wa_, const float* __restrict__ ba_,
    const _Float16* __restrict__ W1T, const float* __restrict__ b1,
    const _Float16* __restrict__ W2T, const float* __restrict__ b2,
    float* __restrict__ out)
{
    __shared__ _Float16 ldsbuf[2 * 64 * 136];
    __shared__ float cc[64][3];
    __shared__ float red[64][4];
    _Float16 (*As)[136] = (_Float16(*)[136])ldsbuf;
    _Float16 (*Ss)[136] = (_Float16(*)[136])(ldsbuf + 64 * 136);
    _Float16 (*Fs)[136] = As;   // alias
    _Float16 (*Z)[136]  = Ss;   // alias

    const int tid = threadIdx.x;
    const int n0 = blockIdx.x * 64;
    const int lane = tid & 63;
    const int wv = tid >> 6;
    const int q = lane >> 4;
    const int lb = lane & 15;
    const int w32 = wv * 32;

    if (tid < 64) {
        const float* xr = x + (size_t)(n0 + tid) * XSTRIDE;
        cc[tid][0] = 2.0f * xr[0];
        cc[tid][1] = xr[1];
        cc[tid][2] = xr[2];
    }
    STAGE_TILE(As, Fp, n0, tid)
    STAGE_TILE(Ss, Sp, n0, tid)
    __syncthreads();

    UPDATE_PHASE_A_LDS(Wa_, ba_)

    // ---- Phase B: z = F2 @ W1 + b1 (A from LDS Fs) ----
    frag_cd az[4][2];
    #pragma unroll
    for (int nt = 0; nt < 4; ++nt)
        #pragma unroll
        for (int ct = 0; ct < 2; ++ct)
            az[nt][ct] = (frag_cd){0.f, 0.f, 0.f, 0.f};

    frag_h bZ[4][2];
    #pragma unroll
    for (int c = 0; c < 4; ++c)
        #pragma unroll
        for (int ct = 0; ct < 2; ++ct)
            bZ[c][ct] = *(const frag_h*)(
                W1T + (size_t)(w32 + ct * 16 + lb) * 128 + c * 32 + q * 8);

    #pragma unroll
    for (int c = 0; c < 4; ++c) {
        frag_h aZ[4];
        #pragma unroll
        for (int nt = 0; nt < 4; ++nt)
            aZ[nt] = *(const frag_h*)&Fs[nt * 16 + lb][c * 32 + q * 8];
        #pragma unroll
        for (int ct = 0; ct < 2; ++ct)
            #pragma unroll
            for (int nt = 0; nt < 4; ++nt)
                az[nt][ct] = __builtin_amdgcn_mfma_f32_16x16x32_f16(
                    aZ[nt], bZ[c][ct], az[nt][ct], 0, 0, 0);
    }
    __syncthreads();   // Ss K-loop reads done block-wide before Z overwrite
    #pragma unroll
    for (int ct = 0; ct < 2; ++ct) {
        int col = w32 + ct * 16 + lb;
        float bb = b1[col];
        #pragma unroll
        for (int nt = 0; nt < 4; ++nt)
            #pragma unroll
            for (int rg = 0; rg < 4; ++rg)
                Z[nt * 16 + q * 4 + rg][col] = (_Float16)(az[nt][ct][rg] + bb);
    }
    __syncthreads();

    // ---- Phase C: logits = z@W2 + b2 (wave = 16-row tile), log_softmax ----
    frag_cd a2[3];
    #pragma unroll
    for (int ct = 0; ct < 3; ++ct) a2[ct] = (frag_cd){0.f, 0.f, 0.f, 0.f};
    #pragma unroll
    for (int ch = 0; ch < 4; ++ch) {
        frag_h zF = *(const frag_h*)&Z[wv * 16 + lb][ch * 32 + q * 8];
        #pragma unroll
        for (int ct = 0; ct < 3; ++ct) {
            frag_h bF = *(const frag_h*)(W2T + (size_t)(ct * 16 + lb) * 128 + ch * 32 + q * 8);
            a2[ct] = __builtin_amdgcn_mfma_f32_16x16x32_f16(zF, bF, a2[ct], 0, 0, 0);
        }
    }

    float lg[3][4];
    #pragma unroll
    for (int ct = 0; ct < 3; ++ct) {
        int col = ct * 16 + lb;
        bool valid = col < 40;
        float bb = valid ? b2[col] : -1e30f;
        #pragma unroll
        for (int rg = 0; rg < 4; ++rg)
            lg[ct][rg] = valid ? (a2[ct][rg] + bb) : -1e30f;
    }
    #pragma unroll
    for (int rg = 0; rg < 4; ++rg) {
        float mx = fmaxf(fmaxf(lg[0][rg], lg[1][rg]), lg[2][rg]);
        #pragma unroll
        for (int m = 1; m < 16; m <<= 1) mx = fmaxf(mx, __shfl_xor(mx, m, 64));
        float sm = __expf(lg[0][rg] - mx) + __expf(lg[1][rg] - mx) + __expf(lg[2][rg] - mx);
        #pragma unroll
        for (int m = 1; m < 16; m <<= 1) sm += __shfl_xor(sm, m, 64);
        float ls = mx + __logf(sm);
        int row = n0 + wv * 16 + q * 4 + rg;
        #pragma unroll
        for (int ct = 0; ct < 3; ++ct) {
            int col = ct * 16 + lb;
            if (col < 40) out[(size_t)row * 40 + col] = lg[ct][rg] - ls;
        }
    }
}

extern "C" void kernel_launch(void* const* d_in, const int* in_sizes, int n_in,
                              void* d_out, int out_size, void* d_ws, size_t ws_size,
                              hipStream_t stream) {
    const float* x  = (const float*)d_in[0];
    const int*   ei = (const int*)d_in[1];
    const float* Wm = (const float*)d_in[2];
    const float* bm = (const float*)d_in[3];
    const float* Wa = (const float*)d_in[4];
    const float* ba = (const float*)d_in[5];
    const float* W1 = (const float*)d_in[6];
    const float* b1 = (const float*)d_in[7];
    const float* W2 = (const float*)d_in[8];
    const float* b2 = (const float*)d_in[9];
    float* out = (float*)d_out;

    const int N = in_sizes[0] / XSTRIDE;   // 40000
    const int E = in_sizes[1] / 2;         // 480000
    const int NB = (N + 255) / 256;        // 157
    const size_t P = (size_t)N * 128;      // plane elements

    // workspace carve (16B-aligned)
    _Float16* Mb  = (_Float16*)d_ws;       // msg fp16
    _Float16* X   = Mb + P;                // x feats fp16
    _Float16* S   = X + P;                 // aggr fp16
    _Float16* F1  = S + P;                 // layer-1 out fp16
    _Float16* WmT = F1 + P;
    _Float16* WaT = WmT + CW_M;
    _Float16* W1T = WaT + CW_A;
    _Float16* W2T = W1T + CW_1;
    int* cnt   = (int*)(W2T + CW_2);       // N (memset together with fc)
    int* fc    = cnt + N;                  // N
    int* offs  = fc + N;                   // N+1
    int* csr   = offs + N + 1;             // E
    int* bsums = csr + E;                  // NB

    // ---- prep: zero counters, then merged convert+count ----
    hipMemsetAsync(cnt, 0, (size_t)2 * N * sizeof(int), stream);
    const int prep_total = CW_TOT + N * 16 + E;
    prep_kernel<<<(prep_total + 255) / 256, 256, 0, stream>>>(
        Wm, Wa, W1, W2, WmT, WaT, W1T, W2T, x, X, ei, cnt, N, E);

    // ---- CSR offsets: scanA -> scanC(inline scanB) ----
    scanA<<<NB, 256, 0, stream>>>(cnt, N, bsums);
    scanC<<<NB, 256, 0, stream>>>(cnt, N, NB, bsums, offs);

    const int gblk = N / 64;               // 625
    const int ablk = (N + 15) / 16;        // 2500
    const int fillB = (E + 255) / 256;     // 1875

    // layer-1 msg GEMM + CSR fill (merged dispatch; independent work)
    msg_fill_kernel<<<gblk + fillB, 256, 0, stream>>>(
        x, X, WmT, bm, Mb, ei, E, offs, fc, csr, gblk);
    agg_kernel<<<ablk, 256, 0, stream>>>(csr, offs, Mb, S, N);
    // layer-1 update + layer-2 msg (fused)
    fused_upd_msg<<<gblk, 256, 0, stream>>>(
        x, X, S, WaT, ba,
        WmT + (size_t)3 * 128 * 128, bm + (size_t)4 * 128, F1, Mb);
    agg_kernel<<<ablk, 256, 0, stream>>>(csr, offs, Mb, S, N);
    // layer-2 update + final MLP + log_softmax (fused)
    fused_upd_final<<<gblk, 256, 0, stream>>>(
        x, F1, S, WaT + (size_t)3 * 128 * 256, ba + (size_t)4 * 128,
        W1T, b1, W2T, b2, out);
}